// Round 18
// baseline (110.603 us; speedup 1.0000x reference)
//
#include <hip/hip_runtime.h>

// PINN jets via MFMA, round 18: r17 (passed, 108.5 us) minus dead VALU:
//   1. ZERO-register peeling: first MFMA of every accumulator chain reads a
//      never-written fz={0,0,0,0} as C -> ~700 per-wave zero-init movs gone.
//   2. Fragment arrays init'd once at declaration (fully overwritten per
//      layer -> per-layer re-zeroing removed; fhU keeps init: kt=3 partial).
//   3. Prep writes PADDED f32 params (W1,b1..b5 ->64, bout ->112) into ws
//      tail -> all bias/W1 loads are unconditional float4 (edge branches gone).
// Math bit-identical to r17 (pads produce identical zeros).
//
// Structure: transposed network (zero cross-lane), fast K=32 MFMA, slot-
// permuted K, precision-tiered (jet0 3/jet1 2/jet2,3 1-term; head a0 3/
// a1 2/a3 1; final F 1-term, Mdt 2-term), zero-LDS, 128-thread/2-wave
// blocks, __launch_bounds__(128,3) (VGPR cap ~85; r16 lesson: min-waves
// arg SETS the cap ~=256/min_waves -- never exceed true pressure).

typedef float f32x4 __attribute__((ext_vector_type(4)));
typedef short s16x8 __attribute__((ext_vector_type(8)));
typedef unsigned int u32x4 __attribute__((ext_vector_type(4)));

// ws layout (ushort units):
constexpr int WH_LO = 16384, WO_HI = 32768, WO_LO = 39936;
constexpr int MD_HI = 47104, MD_LO = 61440;
constexpr int FWS   = 75776;   // f32 region (ushort offset; 16B aligned)
// f32 region (float units): W1p@0[64], b1p@64[64], b2..b5@128+64L[64 each],
// boutp@384[112]  -> 496 floats total.

__device__ __forceinline__ unsigned short f2b(float v) {
    unsigned int u = __builtin_bit_cast(unsigned int, v);
    unsigned int r = (u + 0x7FFFu + ((u >> 16) & 1u)) >> 16;   // RNE
    return (unsigned short)r;
}
__device__ __forceinline__ float b2f(unsigned short h) {
    return __builtin_bit_cast(float, (unsigned int)h << 16);
}
__device__ __forceinline__ unsigned int cvtpk(float lo, float hi) {
    unsigned int r;
    asm("v_cvt_pk_bf16_f32 %0, %1, %2" : "=v"(r) : "v"(lo), "v"(hi));
    return r;   // low16 = bf16(lo), high16 = bf16(hi)
}
__device__ __forceinline__ void cvt2(float v0, float v1,
                                     unsigned int& hp, unsigned int& lp) {
    hp = cvtpk(v0, v1);
    float r0 = v0 - __builtin_bit_cast(float, hp << 16);
    float r1 = v1 - __builtin_bit_cast(float, hp & 0xFFFF0000u);
    lp = cvtpk(r0, r1);
}
__device__ __forceinline__ s16x8 asfrag(u32x4 u) {
    return __builtin_bit_cast(s16x8, u);
}
__device__ __forceinline__ f32x4 mm(s16x8 a, s16x8 b, f32x4 c) {
    return __builtin_amdgcn_mfma_f32_16x16x32_bf16(a, b, c, 0, 0, 0);
}
__device__ __forceinline__ float ftanh(float z) {
    float e = __expf(2.0f * z);
    float r = __builtin_amdgcn_rcpf(e + 1.0f);
    return fmaf(-2.0f, r, 1.0f);
}

__global__ __launch_bounds__(256) void pinn_prep(
    const float* __restrict__ alpha, const float* __restrict__ beta,
    const float* __restrict__ dtp,
    const float* __restrict__ W1, const float* __restrict__ b1,
    const float* __restrict__ W2, const float* __restrict__ b2,
    const float* __restrict__ W3, const float* __restrict__ b3,
    const float* __restrict__ W4, const float* __restrict__ b4,
    const float* __restrict__ W5, const float* __restrict__ b5,
    const float* __restrict__ Wout, const float* __restrict__ bout,
    unsigned short* __restrict__ wsu)
{
    int i = blockIdx.x * 256 + threadIdx.x;
    float v; int hi_off, lo_off;
    if (i < 16384) {                                   // hidden W^T A-frags
        int l = i >> 12, r = i & 4095;
        int t = r >> 9, jrt = t >> 1, krt = t & 1;
        int lane = (r >> 3) & 63, e = r & 7;
        int gg = lane >> 4;
        int j = 16 * jrt + (lane & 15);
        int n = 32 * krt + 16 * (e >> 2) + 4 * gg + (e & 3);
        const float* W = (l == 0) ? W2 : (l == 1) ? W3 : (l == 2) ? W4 : W5;
        v = (n < 50 && j < 50) ? W[n * 50 + j] : 0.0f;
        hi_off = i; lo_off = i + WH_LO;
    } else if (i < 23552) {                            // Wout^T A-frags
        int r = i - 16384;
        int t = r >> 9, jrt = t >> 1, krt = t & 1;
        int lane = (r >> 3) & 63, e = r & 7;
        int gg = lane >> 4;
        int j = 16 * jrt + (lane & 15);
        int n = 32 * krt + 16 * (e >> 2) + 4 * gg + (e & 3);
        v = (n < 50 && j < 100) ? Wout[n * 100 + j] : 0.0f;
        hi_off = WO_HI + r; lo_off = WO_LO + r;
    } else if (i < 37888) {                            // Mdt^T A-frags
        int r = i - 23552;
        int t = r >> 9, jrt = t >> 2, kt = t & 3;
        int lane = (r >> 3) & 63, e = r & 7;
        int gg = lane >> 4;
        int j = 16 * jrt + (lane & 15);
        int k = 32 * kt + 16 * (e >> 2) + 4 * gg + (e & 3);
        v = (j < 100 && k < 100) ? dtp[0] * (beta[k] - alpha[j * 100 + k]) : 0.0f;
        hi_off = MD_HI + r; lo_off = MD_LO + r;
    } else if (i < 38384) {                            // padded f32 params
        int r = i - 37888;
        float* fws = (float*)(wsu + FWS);
        float v2;
        if (r < 64)       v2 = (r < 50) ? W1[r] : 0.0f;
        else if (r < 128) v2 = ((r - 64) < 50) ? b1[r - 64] : 0.0f;
        else if (r < 384) {
            int L = (r - 128) >> 6, jj = (r - 128) & 63;
            const float* bb = (L == 0) ? b2 : (L == 1) ? b3 : (L == 2) ? b4 : b5;
            v2 = (jj < 50) ? bb[jj] : 0.0f;
        } else {
            int jj = r - 384;                          // r in [384, 496)
            v2 = (jj < 100) ? bout[jj] : 0.0f;
        }
        fws[r] = v2;
        return;
    } else return;
    unsigned short h = f2b(v);
    wsu[hi_off] = h;
    wsu[lo_off] = f2b(v - b2f(h));
}

// One hidden layer, tiered, ZERO-peeled chains, padded-bias float4 loads.
__device__ __forceinline__ void hidden_layer(
    const unsigned short* __restrict__ wsu, int Lb,
    const float* __restrict__ biasp,   // padded 64-float bias
    int ln, int gg, f32x4 fz,
    const u32x4 (&gh)[2][4], const u32x4 (&gl0)[2],
    u32x4 (&nh)[2][4], u32x4 (&nl0)[2])
{
#pragma unroll
    for (int jrt = 0; jrt < 4; ++jrt) {
        s16x8 wh0 = *(const s16x8*)(wsu + Lb + (jrt * 2) * 512 + ln * 8);
        s16x8 wl0 = *(const s16x8*)(wsu + WH_LO + Lb + (jrt * 2) * 512 + ln * 8);
        s16x8 wh1 = *(const s16x8*)(wsu + Lb + (jrt * 2 + 1) * 512 + ln * 8);
        s16x8 wl1 = *(const s16x8*)(wsu + WH_LO + Lb + (jrt * 2 + 1) * 512 + ln * 8);
        // krt=0 peeled into fz, krt=1 accumulates
        f32x4 accA0 = mm(wh0, asfrag(gh[0][0]), fz);        // jet0: 3-term
        f32x4 accB0a = mm(wh0, asfrag(gl0[0]), fz);
        f32x4 accB0b = mm(wl0, asfrag(gh[0][0]), fz);
        f32x4 accA1 = mm(wh0, asfrag(gh[0][1]), fz);        // jet1: 2-term
        f32x4 accB1 = mm(wl0, asfrag(gh[0][1]), fz);
        f32x4 accA2 = mm(wh0, asfrag(gh[0][2]), fz);        // jet2: 1-term
        f32x4 accA3 = mm(wh0, asfrag(gh[0][3]), fz);        // jet3: 1-term
        accA0 = mm(wh1, asfrag(gh[1][0]), accA0);
        accB0a = mm(wh1, asfrag(gl0[1]), accB0a);
        accB0b = mm(wl1, asfrag(gh[1][0]), accB0b);
        accA1 = mm(wh1, asfrag(gh[1][1]), accA1);
        accB1 = mm(wl1, asfrag(gh[1][1]), accB1);
        accA2 = mm(wh1, asfrag(gh[1][2]), accA2);
        accA3 = mm(wh1, asfrag(gh[1][3]), accA3);
        float4 bv4 = *(const float4*)&biasp[16 * jrt + 4 * gg];
        float bv[4] = {bv4.x, bv4.y, bv4.z, bv4.w};
        float m[4][4];
#pragma unroll
        for (int r = 0; r < 4; ++r) {
            float z0 = (accA0[r] + accB0a[r]) + (accB0b[r] + bv[r]);
            float z1 = accA1[r] + accB1[r];
            float z2 = accA2[r];
            float z3 = accA3[r];
            float t  = ftanh(z0);
            float sd = fmaf(-t, t, 1.0f);
            float c2 = -2.0f * t * sd;
            float c3 = -2.0f * sd * fmaf(3.0f, sd, -2.0f);
            float z1sq = z1 * z1;
            m[0][r] = t;
            m[1][r] = sd * z1;
            m[2][r] = fmaf(c2, z1sq, sd * z2);
            m[3][r] = fmaf(c3, z1sq * z1, fmaf(3.0f * c2, z1 * z2, sd * z3));
        }
        const int kd = jrt >> 1, p = jrt & 1;
        {   // jet0: hi + lo
            unsigned int hp0, lp0, hp1, lp1;
            cvt2(m[0][0], m[0][1], hp0, lp0);
            cvt2(m[0][2], m[0][3], hp1, lp1);
            nh[kd][0][2 * p]     = hp0;
            nh[kd][0][2 * p + 1] = hp1;
            nl0[kd][2 * p]       = lp0;
            nl0[kd][2 * p + 1]   = lp1;
        }
#pragma unroll
        for (int ct = 1; ct < 4; ++ct) {                    // jets 1-3: hi only
            nh[kd][ct][2 * p]     = cvtpk(m[ct][0], m[ct][1]);
            nh[kd][ct][2 * p + 1] = cvtpk(m[ct][2], m[ct][3]);
        }
    }
}

__global__ __launch_bounds__(128, 3) void pinn_main(
    const float* __restrict__ X, int N,
    const float* __restrict__ l1p, const float* __restrict__ l2p,
    const unsigned short* __restrict__ wsu,
    float* __restrict__ out)
{
    const int tid = threadIdx.x;
    const int wv = tid >> 6, ln = tid & 63;
    const int cc = ln & 15, gg = ln >> 4;
    const int n0 = blockIdx.x * 32 + wv * 16;
    const float* fws = (const float*)(wsu + FWS);
    const f32x4 fz = {0.f, 0.f, 0.f, 0.f};

    // fragment arrays: one-time defined init (fully overwritten per layer)
    u32x4 gAh[2][4] = {}, gAl0[2] = {}, gBh[2][4] = {}, gBl0[2] = {};

    // ---- layer 1: width 1 -> 50, jets (x,1,0,0), padded float4 W1/b1 ----
    float x = (n0 + cc < N) ? X[n0 + cc] : 0.0f;
#pragma unroll
    for (int krt = 0; krt < 2; ++krt)
#pragma unroll
        for (int jf = 0; jf < 2; ++jf) {
            float4 w4 = *(const float4*)&fws[32 * krt + 16 * jf + 4 * gg];
            float4 b4 = *(const float4*)&fws[64 + 32 * krt + 16 * jf + 4 * gg];
            float wv_[4] = {w4.x, w4.y, w4.z, w4.w};
            float bv_[4] = {b4.x, b4.y, b4.z, b4.w};
            float m[4][4];
#pragma unroll
            for (int q = 0; q < 4; ++q) {
                float w = wv_[q];
                float z0 = fmaf(x, w, bv_[q]);
                float t  = ftanh(z0);
                float sd = fmaf(-t, t, 1.0f);
                float c2 = -2.0f * t * sd;
                float c3 = -2.0f * sd * fmaf(3.0f, sd, -2.0f);
                float w2 = w * w;
                m[0][q] = t; m[1][q] = sd * w; m[2][q] = c2 * w2; m[3][q] = c3 * w2 * w;
            }
            {
                unsigned int hp0, lp0, hp1, lp1;
                cvt2(m[0][0], m[0][1], hp0, lp0);
                cvt2(m[0][2], m[0][3], hp1, lp1);
                gAh[krt][0][2 * jf]     = hp0;
                gAh[krt][0][2 * jf + 1] = hp1;
                gAl0[krt][2 * jf]       = lp0;
                gAl0[krt][2 * jf + 1]   = lp1;
            }
#pragma unroll
            for (int ct = 1; ct < 4; ++ct) {
                gAh[krt][ct][2 * jf]     = cvtpk(m[ct][0], m[ct][1]);
                gAh[krt][ct][2 * jf + 1] = cvtpk(m[ct][2], m[ct][3]);
            }
        }

    // ---- layers 2..5 (A->B->A->B->A) ----
#pragma unroll 1
    for (int L = 0; L < 2; ++L) {
        hidden_layer(wsu, (2 * L) * 4096,     fws + 128 + 64 * (2 * L),
                     ln, gg, fz, gAh, gAl0, gBh, gBl0);
        hidden_layer(wsu, (2 * L + 1) * 4096, fws + 128 + 64 * (2 * L + 1),
                     ln, gg, fz, gBh, gBl0, gAh, gAl0);
    }

    // ---- head: a0 3-term (peeled), a1 2-term, a3 1-term; u0 in regs ----
    const float l1v = l1p[0], l2v = l2p[0];
    float u0s[7][4];
    u32x4 fhU[4];
#pragma unroll
    for (int kt = 0; kt < 4; ++kt) fhU[kt] = (u32x4){0u, 0u, 0u, 0u};
#pragma unroll
    for (int jrt = 0; jrt < 7; ++jrt) {
        s16x8 wh0 = *(const s16x8*)(wsu + WO_HI + (jrt * 2) * 512 + ln * 8);
        s16x8 wl0 = *(const s16x8*)(wsu + WO_LO + (jrt * 2) * 512 + ln * 8);
        s16x8 wh1 = *(const s16x8*)(wsu + WO_HI + (jrt * 2 + 1) * 512 + ln * 8);
        s16x8 wl1 = *(const s16x8*)(wsu + WO_LO + (jrt * 2 + 1) * 512 + ln * 8);
        f32x4 a0A = mm(wh0, asfrag(gAh[0][0]), fz);
        f32x4 a0B = mm(wh0, asfrag(gAl0[0]), fz);
        f32x4 a0C = mm(wl0, asfrag(gAh[0][0]), fz);
        f32x4 a1A = mm(wh0, asfrag(gAh[0][1]), fz);
        f32x4 a1B = mm(wl0, asfrag(gAh[0][1]), fz);
        f32x4 a3A = mm(wh0, asfrag(gAh[0][3]), fz);
        a0A = mm(wh1, asfrag(gAh[1][0]), a0A);
        a0B = mm(wh1, asfrag(gAl0[1]), a0B);
        a0C = mm(wl1, asfrag(gAh[1][0]), a0C);
        a1A = mm(wh1, asfrag(gAh[1][1]), a1A);
        a1B = mm(wl1, asfrag(gAh[1][1]), a1B);
        a3A = mm(wh1, asfrag(gAh[1][3]), a3A);
        float4 bo4 = *(const float4*)&fws[384 + 16 * jrt + 4 * gg];
        float bo[4] = {bo4.x, bo4.y, bo4.z, bo4.w};
        float fv[4];
#pragma unroll
        for (int r = 0; r < 4; ++r) {
            float u0 = (a0A[r] + a0B[r]) + (a0C[r] + bo[r]);
            u0s[jrt][r] = u0;
            fv[r] = -(l1v * u0) * (a1A[r] + a1B[r]) - l2v * a3A[r];
        }
        const int kt = jrt >> 1, p = jrt & 1;
        fhU[kt][2 * p]     = cvtpk(fv[0], fv[1]);
        fhU[kt][2 * p + 1] = cvtpk(fv[2], fv[3]);
    }

    // ---- final: out = u0 + Mdt^T @ F^T (F 1-term, Mdt 2-term, peeled) ----
    const bool act = (n0 + cc) < N;
    float* orow = out + (size_t)(n0 + cc) * 100;
#pragma unroll
    for (int jrt = 0; jrt < 7; ++jrt) {
        s16x8 fb0 = asfrag(fhU[0]), fb1 = asfrag(fhU[1]);
        s16x8 fb2 = asfrag(fhU[2]), fb3 = asfrag(fhU[3]);
        s16x8 mh0 = *(const s16x8*)(wsu + MD_HI + (jrt * 4 + 0) * 512 + ln * 8);
        s16x8 ml0 = *(const s16x8*)(wsu + MD_LO + (jrt * 4 + 0) * 512 + ln * 8);
        s16x8 mh1 = *(const s16x8*)(wsu + MD_HI + (jrt * 4 + 1) * 512 + ln * 8);
        s16x8 ml1 = *(const s16x8*)(wsu + MD_LO + (jrt * 4 + 1) * 512 + ln * 8);
        s16x8 mh2 = *(const s16x8*)(wsu + MD_HI + (jrt * 4 + 2) * 512 + ln * 8);
        s16x8 ml2 = *(const s16x8*)(wsu + MD_LO + (jrt * 4 + 2) * 512 + ln * 8);
        s16x8 mh3 = *(const s16x8*)(wsu + MD_HI + (jrt * 4 + 3) * 512 + ln * 8);
        s16x8 ml3 = *(const s16x8*)(wsu + MD_LO + (jrt * 4 + 3) * 512 + ln * 8);
        f32x4 accA = mm(mh0, fb0, fz);
        f32x4 accB = mm(ml0, fb0, fz);
        f32x4 accC = mm(mh1, fb1, fz);
        f32x4 accD = mm(ml1, fb1, fz);
        accA = mm(mh2, fb2, accA);
        accB = mm(ml2, fb2, accB);
        accC = mm(mh3, fb3, accC);
        accD = mm(ml3, fb3, accD);
        if (act && (jrt < 6 || gg == 0)) {
            float4 v = make_float4(
                u0s[jrt][0] + (accA[0] + accB[0]) + (accC[0] + accD[0]),
                u0s[jrt][1] + (accA[1] + accB[1]) + (accC[1] + accD[1]),
                u0s[jrt][2] + (accA[2] + accB[2]) + (accC[2] + accD[2]),
                u0s[jrt][3] + (accA[3] + accB[3]) + (accC[3] + accD[3]));
            *(float4*)(orow + 16 * jrt + 4 * gg) = v;
        }
    }
}

extern "C" void kernel_launch(void* const* d_in, const int* in_sizes, int n_in,
                              void* d_out, int out_size, void* d_ws, size_t ws_size,
                              hipStream_t stream)
{
    const float* X     = (const float*)d_in[0];
    const float* dt    = (const float*)d_in[1];
    const float* alpha = (const float*)d_in[2];
    const float* beta  = (const float*)d_in[3];
    const float* W1    = (const float*)d_in[4];
    const float* b1    = (const float*)d_in[5];
    const float* W2    = (const float*)d_in[6];
    const float* b2    = (const float*)d_in[7];
    const float* W3    = (const float*)d_in[8];
    const float* b3    = (const float*)d_in[9];
    const float* W4    = (const float*)d_in[10];
    const float* b4    = (const float*)d_in[11];
    const float* W5    = (const float*)d_in[12];
    const float* b5    = (const float*)d_in[13];
    const float* Wout  = (const float*)d_in[14];
    const float* bout  = (const float*)d_in[15];
    const float* l1    = (const float*)d_in[16];
    const float* l2    = (const float*)d_in[17];

    unsigned short* wsu = (unsigned short*)d_ws;
    int N = in_sizes[0];

    pinn_prep<<<150, 256, 0, stream>>>(alpha, beta, dt, W1, b1, W2, b2, W3, b3,
                                       W4, b4, W5, b5, Wout, bout, wsu);

    int grid = (N + 31) / 32;
    pinn_main<<<grid, 128, 0, stream>>>(X, N, l1, l2, wsu, (float*)d_out);
}